// Round 10
// baseline (445.596 us; speedup 1.0000x reference)
//
#include <hip/hip_runtime.h>
#include <hip/hip_bf16.h>

// Problem constants
#define BB 8
#define SS 2048
#define DD 1024
#define OO 1024
#define MM (BB * SS)   // 16384
#define KK DD          // 1024
#define NN OO          // 1024
#define CC 64          // chunks
#define LL 32          // chunk length (CC*LL == SS)

typedef __bf16 bf16x8 __attribute__((ext_vector_type(8)));
typedef __bf16 bf16x2 __attribute__((ext_vector_type(2)));
typedef float floatx4 __attribute__((ext_vector_type(4)));

__device__ __forceinline__ float2 fma2(float2 h, float2 a, float2 v) {
    h.x = fmaf(h.x, a.x, v.x);
    h.y = fmaf(h.y, a.y, v.y);
    return h;
}

// ---------------- Fused scan: local carry + publish + transpose + poll + prefix + emit ----------
// 512 blocks x 512 thr (>= 2 blocks/CU capacity; deps only on LOWER block
// ids => deadlock-free under ascending dispatch even at 1/CU).
// Sync fix vs R7 (327us): polls are read-only device-scope atomic LOADS
// (no RMW serialization); <=63 pollers, each on a DISTINCT word.
// Publish: carry stores -> __threadfence -> __syncthreads -> release-store.
// Consume: acquire-load poll -> __syncthreads -> __threadfence -> reads
// (carry lines are first-touch after the fence => served from the coherent
// point, where the producer's agent-scope fence pushed them).
// BC transpose (2 tiles/block) sits between publish and poll: latency filler.
// All fma chains byte-identical to the verified split kernels.
__global__ __launch_bounds__(512) void scan_fused2(const float* __restrict__ x,
                                                   const float* __restrict__ A,
                                                   float* __restrict__ carry,
                                                   const float* __restrict__ BC,
                                                   __bf16* __restrict__ BCt,
                                                   __bf16* __restrict__ hs,
                                                   unsigned int* __restrict__ flags) {
    __shared__ float tile[32][33];
    const int id = blockIdx.x;      // 0..511 == (b,c)
    const int c = id & (CC - 1);
    const int b = id >> 6;
    const int i2 = threadIdx.x;     // float2 index over D (0..511)
    const float2 a = ((const float2*)A)[i2];
    const size_t base = ((size_t)b * SS + (size_t)c * LL) * DD;
    const float2* xp = (const float2*)(x + base) + i2;

    // ---- (1) local chunk scan -> carry
    {
        float2 h = make_float2(0.f, 0.f);
#pragma unroll
        for (int t0 = 0; t0 < LL; t0 += 8) {
            float2 v[8];
#pragma unroll
            for (int u = 0; u < 8; ++u) v[u] = xp[(size_t)(t0 + u) * (DD / 2)];
#pragma unroll
            for (int u = 0; u < 8; ++u) h = fma2(h, a, v[u]);
        }
        ((float2*)carry)[((size_t)b * CC + c) * (DD / 2) + i2] = h;
    }

    // ---- (2) publish
    __threadfence();
    __syncthreads();
    if (threadIdx.x == 0)
        __hip_atomic_store(&flags[id], 1u, __ATOMIC_RELEASE, __HIP_MEMORY_SCOPE_AGENT);

    // ---- (3) BC transpose+cast: 2 of 1024 32x32 tiles (latency filler)
    {
        const int tx = threadIdx.x & 31;
        const int ty = threadIdx.x >> 5;   // 0..15
#pragma unroll
        for (int w = 0; w < 2; ++w) {
            const int t = id * 2 + w;
            const int o0 = (t & 31) * 32;
            const int d0 = (t >> 5) * 32;
            __syncthreads();
#pragma unroll
            for (int i = 0; i < 2; ++i) {
                const int dd = ty + i * 16;
                tile[dd][tx] = BC[(size_t)(d0 + dd) * OO + o0 + tx];
            }
            __syncthreads();
#pragma unroll
            for (int i = 0; i < 2; ++i) {
                const int oo = ty + i * 16;
                BCt[(size_t)(o0 + oo) * DD + d0 + tx] = (__bf16)tile[tx][oo];
            }
        }
    }

    // ---- (4) poll predecessors: thread j<c polls flag j (read-only loads)
    if ((int)threadIdx.x < c) {
        while (__hip_atomic_load(&flags[(b << 6) + (int)threadIdx.x],
                                 __ATOMIC_ACQUIRE, __HIP_MEMORY_SCOPE_AGENT) == 0u)
            __builtin_amdgcn_s_sleep(1);
    }
    __syncthreads();
    __threadfence();

    // ---- (5) chunk prefix (batched 8-deep, ascending j: same rounding)
    float2 aL = a;
#pragma unroll
    for (int i = 0; i < 5; ++i) { aL.x *= aL.x; aL.y *= aL.y; }   // a^32
    float2 h = make_float2(0.f, 0.f);
    const float2* cp = (const float2*)carry + (size_t)b * CC * (DD / 2) + i2;
    int j = 0;
    for (; j + 8 <= c; j += 8) {
        float2 cv[8];
#pragma unroll
        for (int u = 0; u < 8; ++u) cv[u] = cp[(size_t)(j + u) * (DD / 2)];
#pragma unroll
        for (int u = 0; u < 8; ++u) h = fma2(h, aL, cv[u]);
    }
    for (; j < c; ++j) h = fma2(h, aL, cp[(size_t)j * (DD / 2)]);

    // ---- (6) emit hs (x re-read L2/L3-hot from step 1)
    bf16x2* hp = (bf16x2*)(hs + base) + i2;
#pragma unroll
    for (int t0 = 0; t0 < LL; t0 += 8) {
        float2 v[8];
#pragma unroll
        for (int u = 0; u < 8; ++u) v[u] = xp[(size_t)(t0 + u) * (DD / 2)];
#pragma unroll
        for (int u = 0; u < 8; ++u) {
            h = fma2(h, a, v[u]);
            bf16x2 o;
            o[0] = (__bf16)h.x; o[1] = (__bf16)h.y;
            hp[(size_t)(t0 + u) * (DD / 2)] = o;
        }
    }
}

// ---------------- GEMM: C[m,n] = sum_k A[m,k] * Bt[n,k] ----------------
// (byte-identical to round 6 — best verified: 46.6 us, SQ_LDS_BANK_CONFLICT=0)
// 256x256 tile, BK=64, 8 waves (2Mx4N). ONE vmcnt(0) + ONE barrier per
// K-tile, all stages strictly AFTER the barrier.
#define GTM 256
#define GTN 256
#define GTK 64
#define GNT (KK / GTK)   // 16

__device__ __forceinline__ void async16(void* lds, const void* g) {
    __builtin_amdgcn_global_load_lds(
        (__attribute__((address_space(1))) void*)(void*)g,
        (__attribute__((address_space(3))) void*)lds, 16, 0, 0);
}

#define MEMFENCE asm volatile("" ::: "memory")
#define BARRIER do { MEMFENCE; __builtin_amdgcn_s_barrier(); MEMFENCE; } while (0)
#define VMCNT0 asm volatile("s_waitcnt vmcnt(0)" ::: "memory")

__global__ __launch_bounds__(512, 2) void gemm_bt(const __bf16* __restrict__ Am,
                                                  const __bf16* __restrict__ Bt,
                                                  float* __restrict__ C) {
    __shared__ __align__(16) __bf16 As[2][GTM * GTK];   // 2 x 32 KB
    __shared__ __align__(16) __bf16 Bs[2][GTN * GTK];   // 2 x 32 KB

    const int tid = threadIdx.x;          // 0..511
    const int wave = tid >> 6;            // 0..7
    const int lane = tid & 63;
    const int wm = (wave >> 2) * 128;     // 0 / 128
    const int wn = (wave & 3) * 64;       // 0,64,128,192
    const int lanelo = lane & 15;
    const int quad = lane >> 4;

    // XCD-chunked swizzle (FETCH_SIZE 38->24.6 MB)
    const int bid = blockIdx.x;
    const int xcd = bid & 7;
    const int loc = bid >> 3;             // 0..31
    const int tile_m = (xcd * 8 + (loc >> 2)) * GTM;
    const int tile_n = (loc & 3) * GTN;

    // ---- staging pointers: slabs {0:A-M0, 1:B-N0, 2:B-N1, 3:A-M1} x 2 loads
    const __bf16* gsrc[4][2];
    int ldsoff[4][2];
#pragma unroll
    for (int a = 0; a < 2; ++a)
#pragma unroll
        for (int u = 0; u < 2; ++u) {
            const int idx = a * 1024 + u * 512 + tid;   // LDS chunk id
            const int rho = idx >> 3, qs = idx & 7;
            const int rl = rho & 127;
            const int r = (rl >> 6) * 128 + a * 64 + (rl & 63);  // global row
            const int qg = qs ^ (rho & 7);
            gsrc[a * 3][u] = Am + (size_t)(tile_m + r) * KK + qg * 8;
            ldsoff[a * 3][u] = idx * 8;
        }
#pragma unroll
    for (int b = 0; b < 2; ++b)
#pragma unroll
        for (int u = 0; u < 2; ++u) {
            const int idx = b * 1024 + u * 512 + tid;
            const int rho = idx >> 3, qs = idx & 7;
            const int rl = rho & 127;
            const int r = (rl >> 5) * 64 + b * 32 + (rl & 31);   // global row
            const int qg = qs ^ (rho & 7);
            gsrc[1 + b][u] = Bt + (size_t)(tile_n + r) * KK + qg * 8;
            ldsoff[1 + b][u] = idx * 8;
        }

    auto stage = [&](int p, int bufi, int koff) {
        __bf16* base = (p == 0 || p == 3) ? As[bufi] : Bs[bufi];
#pragma unroll
        for (int u = 0; u < 2; ++u)
            async16(base + ldsoff[p][u], gsrc[p][u] + koff);
    };

    floatx4 acc[8][4];
#pragma unroll
    for (int i = 0; i < 8; ++i)
#pragma unroll
        for (int j = 0; j < 4; ++j) acc[i][j] = (floatx4){0.f, 0.f, 0.f, 0.f};

    bf16x8 af[4][2];        // current M-half A fragments
    bf16x8 bv[2][2][2];     // [Nhalf][jl][kk], both halves held

    auto read_a = [&](const __bf16* as, int mh) {
#pragma unroll
        for (int il = 0; il < 4; ++il)
#pragma unroll
            for (int kk = 0; kk < 2; ++kk) {
                const int rho = mh * 128 + (wm >> 1) + il * 16 + lanelo;
                af[il][kk] = *(const bf16x8*)(as + rho * 64 + (((kk * 4 + quad) ^ (lanelo & 7)) * 8));
            }
    };
    auto read_b = [&](const __bf16* bs, int nh) {
#pragma unroll
        for (int jl = 0; jl < 2; ++jl)
#pragma unroll
            for (int kk = 0; kk < 2; ++kk) {
                const int rho = nh * 128 + (wn >> 1) + jl * 16 + lanelo;
                bv[nh][jl][kk] = *(const bf16x8*)(bs + rho * 64 + (((kk * 4 + quad) ^ (lanelo & 7)) * 8));
            }
    };
    auto mfma16 = [&](int mh, int nh) {
        __builtin_amdgcn_s_setprio(1);
#pragma unroll
        for (int il = 0; il < 4; ++il)
#pragma unroll
            for (int jl = 0; jl < 2; ++jl)
#pragma unroll
                for (int kk = 0; kk < 2; ++kk)
                    acc[mh * 4 + il][nh * 2 + jl] = __builtin_amdgcn_mfma_f32_16x16x32_bf16(
                        af[il][kk], bv[nh][jl][kk], acc[mh * 4 + il][nh * 2 + jl], 0, 0, 0);
        __builtin_amdgcn_s_setprio(0);
    };
    auto store_q = [&](int mh, int nh) {
#pragma unroll
        for (int il = 0; il < 4; ++il) {
            const int row = tile_m + wm + (mh * 4 + il) * 16 + quad * 4;
#pragma unroll
            for (int r = 0; r < 4; ++r) {
                float* crow = C + (size_t)(row + r) * NN + tile_n + wn + lanelo;
#pragma unroll
                for (int jl = 0; jl < 2; ++jl)
                    crow[(nh * 2 + jl) * 16] = acc[mh * 4 + il][nh * 2 + jl][r];
            }
        }
    };

    // prologue: tile 0, all 4 slabs -> buf 0 (8 loads in flight)
    stage(0, 0, 0);
    stage(3, 0, 0);
    stage(1, 0, 0);
    stage(2, 0, 0);

    for (int t = 0; t < GNT - 1; ++t) {
        const int cur = t & 1, nxt = cur ^ 1;
        const __bf16* as = As[cur];
        const __bf16* bs = Bs[cur];
        const int ko = (t + 1) * GTK;

        VMCNT0;                   // tile t's 8 loads retired (issued 1 tile ago)
        BARRIER;                  // publish tile t; release buf[nxt] for overwrite

        stage(0, nxt, ko);        // all stages AFTER the barrier
        stage(3, nxt, ko);
        stage(1, nxt, ko);
        stage(2, nxt, ko);

        read_a(as, 0);
        read_b(bs, 0);
        mfma16(0, 0);

        read_b(bs, 1);
        mfma16(0, 1);

        read_a(as, 1);
        mfma16(1, 1);

        mfma16(1, 0);
    }

    // tail tile: drain, then interleave quadrant stores with final MFMAs
    {
        const __bf16* as = As[(GNT - 1) & 1];
        const __bf16* bs = Bs[(GNT - 1) & 1];
        VMCNT0;
        BARRIER;
        read_a(as, 0);
        read_b(bs, 0);
        mfma16(0, 0);
        read_b(bs, 1);
        mfma16(0, 1);
        store_q(0, 0);            // acc[0..3][0..1] final
        read_a(as, 1);
        mfma16(1, 1);
        store_q(0, 1);            // acc[0..3][2..3] final
        mfma16(1, 0);
        store_q(1, 0);
        store_q(1, 1);
    }
}

extern "C" void kernel_launch(void* const* d_in, const int* in_sizes, int n_in,
                              void* d_out, int out_size, void* d_ws, size_t ws_size,
                              hipStream_t stream) {
    const float* x  = (const float*)d_in[0];   // [B,S,D]
    const float* A  = (const float*)d_in[1];   // [D]
    const float* BC = (const float*)d_in[2];   // [D,O]
    float* out = (float*)d_out;                // [B,S,O]

    char* ws = (char*)d_ws;
    __bf16* hs   = (__bf16*)ws;                                  // 33,554,432 B
    float* carry = (float*)(ws + 33554432);                      // 2 MB (BB*CC*DD*4)
    __bf16* BCt  = (__bf16*)(ws + 33554432 + 2097152);           // 2 MB

    // Flags borrow the first 2 KB of the output buffer: zeroed on-stream,
    // consumed by scan_fused2, then fully overwritten by gemm.
    unsigned int* flags = (unsigned int*)d_out;
    hipMemsetAsync(flags, 0, BB * CC * sizeof(unsigned int), stream);

    scan_fused2<<<dim3(BB * CC), 512, 0, stream>>>(x, A, carry, BC, BCt, hs, flags);
    gemm_bt<<<dim3(MM / GTM * (NN / GTN)), 512, 0, stream>>>(hs, BCt, out);
}

// Round 11
// 173.537 us; speedup vs baseline: 2.5677x; 2.5677x over previous
//
#include <hip/hip_runtime.h>
#include <hip/hip_bf16.h>

// Problem constants
#define BB 8
#define SS 2048
#define DD 1024
#define OO 1024
#define MM (BB * SS)   // 16384
#define KK DD          // 1024
#define NN OO          // 1024
#define CC 64          // chunks
#define LL 32          // chunk length (CC*LL == SS)

typedef __bf16 bf16x8 __attribute__((ext_vector_type(8)));
typedef float floatx4 __attribute__((ext_vector_type(4)));

__device__ __forceinline__ float2 fma2(float2 h, float2 a, float2 v) {
    h.x = fmaf(h.x, a.x, v.x);
    h.y = fmaf(h.y, a.y, v.y);
    return h;
}

// ---------------- Kernel 1: per-chunk carries (float2 lanes, 512 thr) + BC transpose ----------------
// (unchanged from round 6 — verified)
__global__ __launch_bounds__(512) void prep(const float* __restrict__ x,
                                            const float* __restrict__ A,
                                            float* __restrict__ carry,
                                            const float* __restrict__ BC,
                                            __bf16* __restrict__ BCt) {
    __shared__ float tile[32][33];
    const int id = blockIdx.x;
    if (id < BB * CC) {
        const int c = id & (CC - 1);
        const int b = id >> 6;          // id / CC
        const int i2 = threadIdx.x;     // float2 index over D (0..511)
        const float2 a = ((const float2*)A)[i2];
        const float2* xp = (const float2*)(x + ((size_t)b * SS + (size_t)c * LL) * DD) + i2;
        float2 h = make_float2(0.f, 0.f);
#pragma unroll
        for (int t0 = 0; t0 < LL; t0 += 8) {
            float2 v[8];
#pragma unroll
            for (int u = 0; u < 8; ++u) v[u] = xp[(size_t)(t0 + u) * (DD / 2)];
#pragma unroll
            for (int u = 0; u < 8; ++u) h = fma2(h, a, v[u]);
        }
        ((float2*)carry)[((size_t)b * CC + c) * (DD / 2) + i2] = h;
    } else {
        const int t = id - BB * CC;        // 0..1023 transpose tiles
        const int o0 = (t & 31) * 32;
        const int d0 = (t >> 5) * 32;
        const int tx = threadIdx.x & 31;
        const int ty = threadIdx.x >> 5;   // 0..15
#pragma unroll
        for (int i = 0; i < 2; ++i) {
            const int dd = ty + i * 16;
            tile[dd][tx] = BC[(size_t)(d0 + dd) * OO + o0 + tx];
        }
        __syncthreads();
#pragma unroll
        for (int i = 0; i < 2; ++i) {
            const int oo = ty + i * 16;
            BCt[(size_t)(o0 + oo) * DD + d0 + tx] = (__bf16)tile[tx][oo];
        }
    }
}

// ---------------- Kernel 2: chunk-start states P[b,c][D] (f32, exact) ----------------
// Identical fma order to the verified scan_emit prefix (batched 8-deep,
// ascending j). P replaces the in-register prefix; f32 store/load round-trip
// is exact, so downstream hs values are bit-identical.
__global__ __launch_bounds__(512) void prefix_k(const float* __restrict__ A,
                                                const float* __restrict__ carry,
                                                float* __restrict__ P) {
    const int id = blockIdx.x;      // 0..511 == b*CC + c
    const int c = id & (CC - 1);
    const int b = id >> 6;
    const int i2 = threadIdx.x;     // float2 index over D
    const float2 a = ((const float2*)A)[i2];
    float2 aL = a;
#pragma unroll
    for (int i = 0; i < 5; ++i) { aL.x *= aL.x; aL.y *= aL.y; }   // a^32
    float2 h = make_float2(0.f, 0.f);
    const float2* cp = (const float2*)carry + (size_t)b * CC * (DD / 2) + i2;
    int j = 0;
    for (; j + 8 <= c; j += 8) {
        float2 cv[8];
#pragma unroll
        for (int u = 0; u < 8; ++u) cv[u] = cp[(size_t)(j + u) * (DD / 2)];
#pragma unroll
        for (int u = 0; u < 8; ++u) h = fma2(h, aL, cv[u]);
    }
    for (; j < c; ++j) h = fma2(h, aL, cp[(size_t)j * (DD / 2)]);
    ((float2*)P)[(size_t)id * (DD / 2) + i2] = h;
}

// ---------------- GEMM with fused scan-emit: C = hs @ BCt^T, hs generated in-kernel ----
// 256x256 tile, BK=64, 8 waves. The A-operand (hs tile [256 s][64 d]) is
// COMPUTED, not loaded: wave w = chunk w (8 chunks per m-tile), lane = d
// (64 diagonal states per k-tile). Per k-tile each lane scans 32 steps from
// P[b, c0+w][d]: h = fmaf(h, a_d, x[s][d]); As <- (__bf16)h. The scan is
// k-tile-independent (diagonal A), so no cross-tile state. fma order, bf16
// cast, and MFMA order are identical to the verified split pipeline ->
// bit-identical C. This deletes scan_emit (64MB x re-read + 32MB hs write)
// and the gemm's hs read, riding the gemm's idle VALU/DS capacity.
// A-LDS: linear rows (row r at LDS row r, 128B stride) with k-chunk XOR
// swizzle: write slot = (d>>3) ^ (t&7); read slot = (kk*4+quad) ^ (lanelo&7)
// (r&7 == t&7 == lanelo&7 across the maps) -> <=2-way bank access.
// B path and sync skeleton byte-identical to round 6 (proven race-free):
// ONE vmcnt(0) + lgkmcnt(0) + barrier per K-tile; stages/scan strictly
// after the barrier; scan writes buf[nxt], reads hit buf[cur].
#define GTM 256
#define GTN 256
#define GTK 64
#define GNT (KK / GTK)   // 16

__device__ __forceinline__ void async16(void* lds, const void* g) {
    __builtin_amdgcn_global_load_lds(
        (__attribute__((address_space(1))) void*)(void*)g,
        (__attribute__((address_space(3))) void*)lds, 16, 0, 0);
}

#define MEMFENCE asm volatile("" ::: "memory")
#define BARRIER do { MEMFENCE; __builtin_amdgcn_s_barrier(); MEMFENCE; } while (0)
#define VMCNT0 asm volatile("s_waitcnt vmcnt(0)" ::: "memory")
#define LGKM0  asm volatile("s_waitcnt lgkmcnt(0)" ::: "memory")

__global__ __launch_bounds__(512, 2) void gemm_bt(const float* __restrict__ x,
                                                  const float* __restrict__ Av,
                                                  const float* __restrict__ P,
                                                  const __bf16* __restrict__ Bt,
                                                  float* __restrict__ C) {
    __shared__ __align__(16) __bf16 As[2][GTM * GTK];   // 2 x 32 KB
    __shared__ __align__(16) __bf16 Bs[2][GTN * GTK];   // 2 x 32 KB

    const int tid = threadIdx.x;          // 0..511
    const int wave = tid >> 6;            // 0..7
    const int lane = tid & 63;
    const int wm = (wave >> 2) * 128;     // 0 / 128
    const int wn = (wave & 3) * 64;       // 0,64,128,192
    const int lanelo = lane & 15;
    const int quad = lane >> 4;

    // XCD-chunked swizzle (verified: FETCH_SIZE 38->24.6 MB)
    const int bid = blockIdx.x;
    const int xcd = bid & 7;
    const int loc = bid >> 3;             // 0..31
    const int tile_m = (xcd * 8 + (loc >> 2)) * GTM;
    const int tile_n = (loc & 3) * GTN;

    // ---- B staging pointers (slabs {B-N0, B-N1}, unchanged layout)
    const __bf16* gsrcB[2][2];
    int ldsoffB[2][2];
#pragma unroll
    for (int b2 = 0; b2 < 2; ++b2)
#pragma unroll
        for (int u = 0; u < 2; ++u) {
            const int idx = b2 * 1024 + u * 512 + tid;
            const int rho = idx >> 3, qs = idx & 7;
            const int rl = rho & 127;
            const int r = (rl >> 5) * 64 + b2 * 32 + (rl & 31);
            const int qg = qs ^ (rho & 7);
            gsrcB[b2][u] = Bt + (size_t)(tile_n + r) * KK + qg * 8;
            ldsoffB[b2][u] = idx * 8;
        }

    auto stageB = [&](int bufi, int koff) {
#pragma unroll
        for (int b2 = 0; b2 < 2; ++b2)
#pragma unroll
            for (int u = 0; u < 2; ++u)
                async16(&Bs[bufi][ldsoffB[b2][u]], gsrcB[b2][u] + koff);
    };

    // ---- scan roles: wave = chunk (8), lane = d (64)
    const int dq = lane >> 3, dlow = lane & 7;
    const int pcw = (tile_m >> 5) + wave;           // global chunk id b*64+c0+w
    const float* xrow = x + (size_t)(tile_m + wave * 32) * DD + lane;

    auto scanA = [&](int kt, int bufi) {
        const int d0 = kt * 64;
        const float a_d = Av[d0 + lane];
        float h = P[(size_t)pcw * DD + d0 + lane];
        const float* xp = xrow + d0;
        __bf16* as = &As[bufi][wave * 32 * 64];
#pragma unroll
        for (int g = 0; g < 4; ++g) {
            float v[8];
#pragma unroll
            for (int u = 0; u < 8; ++u) v[u] = xp[(size_t)(g * 8 + u) * DD];
#pragma unroll
            for (int u = 0; u < 8; ++u) {
                const int t = g * 8 + u;
                h = fmaf(h, a_d, v[u]);                 // same chain as scan_emit
                as[t * 64 + ((dq ^ u) << 3) + dlow] = (__bf16)h;
            }
        }
    };

    floatx4 acc[8][4];
#pragma unroll
    for (int i = 0; i < 8; ++i)
#pragma unroll
        for (int j = 0; j < 4; ++j) acc[i][j] = (floatx4){0.f, 0.f, 0.f, 0.f};

    bf16x8 af[4][2];
    bf16x8 bv[2][2][2];

    auto read_a = [&](const __bf16* as, int mh) {
#pragma unroll
        for (int il = 0; il < 4; ++il)
#pragma unroll
            for (int kk = 0; kk < 2; ++kk) {
                const int row = wm + (mh * 4 + il) * 16 + lanelo;   // linear rows
                af[il][kk] = *(const bf16x8*)(as + row * 64 + (((kk * 4 + quad) ^ (lanelo & 7)) * 8));
            }
    };
    auto read_b = [&](const __bf16* bs, int nh) {
#pragma unroll
        for (int jl = 0; jl < 2; ++jl)
#pragma unroll
            for (int kk = 0; kk < 2; ++kk) {
                const int rho = nh * 128 + (wn >> 1) + jl * 16 + lanelo;
                bv[nh][jl][kk] = *(const bf16x8*)(bs + rho * 64 + (((kk * 4 + quad) ^ (lanelo & 7)) * 8));
            }
    };
    auto mfma16 = [&](int mh, int nh) {
        __builtin_amdgcn_s_setprio(1);
#pragma unroll
        for (int il = 0; il < 4; ++il)
#pragma unroll
            for (int jl = 0; jl < 2; ++jl)
#pragma unroll
                for (int kk = 0; kk < 2; ++kk)
                    acc[mh * 4 + il][nh * 2 + jl] = __builtin_amdgcn_mfma_f32_16x16x32_bf16(
                        af[il][kk], bv[nh][jl][kk], acc[mh * 4 + il][nh * 2 + jl], 0, 0, 0);
        __builtin_amdgcn_s_setprio(0);
    };
    auto store_q = [&](int mh, int nh) {
#pragma unroll
        for (int il = 0; il < 4; ++il) {
            const int row = tile_m + wm + (mh * 4 + il) * 16 + quad * 4;
#pragma unroll
            for (int r = 0; r < 4; ++r) {
                float* crow = C + (size_t)(row + r) * NN + tile_n + wn + lanelo;
#pragma unroll
                for (int jl = 0; jl < 2; ++jl)
                    crow[(nh * 2 + jl) * 16] = acc[mh * 4 + il][nh * 2 + jl][r];
            }
        }
    };

    // ---- prologue: tile 0 (B via gload_lds, A via in-register scan)
    stageB(0, 0);
    scanA(0, 0);

    for (int t = 0; t < GNT; ++t) {
        VMCNT0;                    // B gloads of tile t retired (+ scan x loads, already consumed)
        LGKM0;                     // this wave's A ds_writes of tile t drained
        BARRIER;                   // publish tile t; release buf[nxt]
        const int cur = t & 1, nxt = cur ^ 1;
        const __bf16* as = As[cur];
        const __bf16* bs = Bs[cur];

        if (t + 1 < GNT) {
            stageB(nxt, (t + 1) * GTK);

            read_a(as, 0);
            read_b(bs, 0);
            mfma16(0, 0);
            read_b(bs, 1);
            mfma16(0, 1);
            read_a(as, 1);
            mfma16(1, 1);
            mfma16(1, 0);

            scanA(t + 1, nxt);     // x loads + fma + ds_writes into buf[nxt]
        } else {
            // tail: interleave quadrant stores with final MFMAs
            read_a(as, 0);
            read_b(bs, 0);
            mfma16(0, 0);
            read_b(bs, 1);
            mfma16(0, 1);
            store_q(0, 0);
            read_a(as, 1);
            mfma16(1, 1);
            store_q(0, 1);
            mfma16(1, 0);
            store_q(1, 0);
            store_q(1, 1);
        }
    }
}

extern "C" void kernel_launch(void* const* d_in, const int* in_sizes, int n_in,
                              void* d_out, int out_size, void* d_ws, size_t ws_size,
                              hipStream_t stream) {
    const float* x  = (const float*)d_in[0];   // [B,S,D]
    const float* A  = (const float*)d_in[1];   // [D]
    const float* BC = (const float*)d_in[2];   // [D,O]
    float* out = (float*)d_out;                // [B,S,O]

    char* ws = (char*)d_ws;
    float* P     = (float*)ws;                                   // 2 MB (BB*CC*DD*4)
    float* carry = (float*)(ws + 33554432);                      // 2 MB
    __bf16* BCt  = (__bf16*)(ws + 33554432 + 2097152);           // 2 MB

    prep<<<dim3(BB * CC + 1024), 512, 0, stream>>>(x, A, carry, BC, BCt);
    prefix_k<<<dim3(BB * CC), 512, 0, stream>>>(A, carry, P);
    gemm_bt<<<dim3(MM / GTM * (NN / GTN)), 512, 0, stream>>>(x, A, P, BCt, out);
}